// Round 1
// baseline (3299.322 us; speedup 1.0000x reference)
//
#include <hip/hip_runtime.h>
#include <math.h>

#define BM 64
#define BN 64
#define BK 16
#define PADF 4

// ---------------- block reductions (deterministic tree order) ----------------
static __device__ __forceinline__ float blk_sum(float v) {
    __shared__ float sm[256];
    int tid = threadIdx.x;
    sm[tid] = v; __syncthreads();
#pragma unroll
    for (int s = 128; s > 0; s >>= 1) {
        if (tid < s) sm[tid] += sm[tid + s];
        __syncthreads();
    }
    float r = sm[0]; __syncthreads();
    return r;
}

static __device__ __forceinline__ float blk_max(float v) {
    __shared__ float sm[256];
    int tid = threadIdx.x;
    sm[tid] = v; __syncthreads();
#pragma unroll
    for (int s = 128; s > 0; s >>= 1) {
        if (tid < s) sm[tid] = fmaxf(sm[tid], sm[tid + s]);
        __syncthreads();
    }
    float r = sm[0]; __syncthreads();
    return r;
}

// ---------------- C normalizer: per-row norms of gathered rows ----------------
__global__ __launch_bounds__(256) void k_row_norms(
    const float* __restrict__ X, const int* __restrict__ idx,
    float* __restrict__ norms, int n) {
    long long r = idx[blockIdx.x];
    const float* xr = X + r * (long long)n;
    float s = 0.f;
    for (int k = threadIdx.x * 4; k < n; k += 256 * 4) {
        float4 v = *(const float4*)(xr + k);
        s = fmaf(v.x, v.x, s); s = fmaf(v.y, v.y, s);
        s = fmaf(v.z, v.z, s); s = fmaf(v.w, v.w, s);
    }
    float tot = blk_sum(s);
    if (threadIdx.x == 0) norms[blockIdx.x] = sqrtf(tot);
}

__global__ __launch_bounds__(256) void k_cinv(
    const float* __restrict__ norms, int m, int n, float* __restrict__ cinv) {
    float s = 0.f;
    for (int i = threadIdx.x; i < m; i += 256) s += norms[i];
    float tot = blk_sum(s);
    // C = (sum/m)/sqrt(n)  ->  1/C = m*sqrt(n)/sum
    if (threadIdx.x == 0) cinv[0] = (float)m * sqrtf((float)n) / tot;
}

// ---------------- xs = x * (1/C) ----------------
__global__ __launch_bounds__(256) void k_scale(
    const float* __restrict__ x, const float* __restrict__ cinv,
    float* __restrict__ y, long long total4) {
    float c = cinv[0];
    long long i = blockIdx.x * 256ll + threadIdx.x;
    long long stride = (long long)gridDim.x * 256ll;
    for (; i < total4; i += stride) {
        float4 v = ((const float4*)x)[i];
        v.x *= c; v.y *= c; v.z *= c; v.w *= c;
        ((float4*)y)[i] = v;
    }
}

// ---------------- NT GEMM: C[i][j] = sum_k A[i][k]*B[j][k] ----------------
// Optional row gather (row_idx) + scalar scale (scale_ptr) applied to A.
__global__ __launch_bounds__(256) void k_gemm_nt(
    const float* __restrict__ A, int lda,
    const float* __restrict__ B, int ldb,
    float* __restrict__ C, int ldc, int K,
    const int* __restrict__ row_idx,
    const float* __restrict__ scale_ptr) {
    __shared__ float As[BK][BM + PADF];
    __shared__ float Bs[BK][BN + PADF];
    int tid = threadIdx.x;
    int m0 = blockIdx.x * BM;
    int n0 = blockIdx.y * BN;
    int lr = tid >> 2;             // tile row 0..63
    int lk = (tid & 3) << 2;       // k offset 0,4,8,12
    float scale = scale_ptr ? scale_ptr[0] : 1.0f;
    long long arow = m0 + lr;
    if (row_idx) arow = row_idx[arow];
    const float* Ap = A + arow * (long long)lda + lk;
    const float* Bp = B + (long long)(n0 + lr) * ldb + lk;
    int tx = tid & 15, ty = tid >> 4;
    float acc[4][4] = {{0.f}};
    for (int k0 = 0; k0 < K; k0 += BK) {
        float4 av = *(const float4*)(Ap + k0);
        float4 bv = *(const float4*)(Bp + k0);
        av.x *= scale; av.y *= scale; av.z *= scale; av.w *= scale;
        __syncthreads();
        As[lk + 0][lr] = av.x; As[lk + 1][lr] = av.y;
        As[lk + 2][lr] = av.z; As[lk + 3][lr] = av.w;
        Bs[lk + 0][lr] = bv.x; Bs[lk + 1][lr] = bv.y;
        Bs[lk + 2][lr] = bv.z; Bs[lk + 3][lr] = bv.w;
        __syncthreads();
#pragma unroll
        for (int kk = 0; kk < BK; ++kk) {
            float4 a4 = *(const float4*)&As[kk][ty << 2];
            float4 b4 = *(const float4*)&Bs[kk][tx << 2];
            float avr[4] = {a4.x, a4.y, a4.z, a4.w};
            float bvr[4] = {b4.x, b4.y, b4.z, b4.w};
#pragma unroll
            for (int i = 0; i < 4; ++i)
#pragma unroll
                for (int j = 0; j < 4; ++j)
                    acc[i][j] = fmaf(avr[i], bvr[j], acc[i][j]);
        }
    }
#pragma unroll
    for (int i = 0; i < 4; ++i) {
        float4 o = {acc[i][0], acc[i][1], acc[i][2], acc[i][3]};
        *(float4*)(C + (long long)(m0 + (ty << 2) + i) * ldc + n0 + (tx << 2)) = o;
    }
}

// ---------------- NN GEMM: C[i][j] = sum_k A[i][k]*B[k][j] ----------------
__global__ __launch_bounds__(256) void k_gemm_nn(
    const float* __restrict__ A, int lda,
    const float* __restrict__ B, int ldb,
    float* __restrict__ C, int ldc, int K) {
    __shared__ float As[BK][BM + PADF];
    __shared__ float Bs[BK][BN + PADF];
    int tid = threadIdx.x;
    int m0 = blockIdx.x * BM;
    int n0 = blockIdx.y * BN;
    int lr = tid >> 2;             // A tile row
    int lk = (tid & 3) << 2;       // A k offset
    int bkr = tid >> 4;            // B tile k row 0..15
    int bcq = (tid & 15) << 2;     // B col offset 0..60
    const float* Ap = A + (long long)(m0 + lr) * lda + lk;
    const float* Bp = B + (long long)bkr * ldb + n0 + bcq;
    int tx = tid & 15, ty = tid >> 4;
    float acc[4][4] = {{0.f}};
    for (int k0 = 0; k0 < K; k0 += BK) {
        float4 av = *(const float4*)(Ap + k0);
        float4 bv = *(const float4*)(Bp + (long long)k0 * ldb);
        __syncthreads();
        As[lk + 0][lr] = av.x; As[lk + 1][lr] = av.y;
        As[lk + 2][lr] = av.z; As[lk + 3][lr] = av.w;
        *(float4*)&Bs[bkr][bcq] = bv;
        __syncthreads();
#pragma unroll
        for (int kk = 0; kk < BK; ++kk) {
            float4 a4 = *(const float4*)&As[kk][ty << 2];
            float4 b4 = *(const float4*)&Bs[kk][tx << 2];
            float avr[4] = {a4.x, a4.y, a4.z, a4.w};
            float bvr[4] = {b4.x, b4.y, b4.z, b4.w};
#pragma unroll
            for (int i = 0; i < 4; ++i)
#pragma unroll
                for (int j = 0; j < 4; ++j)
                    acc[i][j] = fmaf(avr[i], bvr[j], acc[i][j]);
        }
    }
#pragma unroll
    for (int i = 0; i < 4; ++i) {
        float4 o = {acc[i][0], acc[i][1], acc[i][2], acc[i][3]};
        *(float4*)(C + (long long)(m0 + (ty << 2) + i) * ldc + n0 + (tx << 2)) = o;
    }
}

// ---------------- row LayerNorm in-place, width W = CNT*256 ----------------
template <int CNT>
__global__ __launch_bounds__(256) void k_layernorm(
    float* __restrict__ Y, const float* __restrict__ g,
    const float* __restrict__ b, int W) {
    float* yr = Y + (long long)blockIdx.x * W;
    float v[CNT];
    float s = 0.f;
#pragma unroll
    for (int i = 0; i < CNT; ++i) {
        v[i] = yr[threadIdx.x + (i << 8)];
        s += v[i];
    }
    float mu = blk_sum(s) / (float)W;
    float sq = 0.f;
#pragma unroll
    for (int i = 0; i < CNT; ++i) {
        float d = v[i] - mu;
        sq = fmaf(d, d, sq);
    }
    float var = blk_sum(sq) / (float)W;
    float rs = rsqrtf(var + 1e-5f);
#pragma unroll
    for (int i = 0; i < CNT; ++i) {
        int col = threadIdx.x + (i << 8);
        yr[col] = (v[i] - mu) * rs * g[col] + b[col];
    }
}

// ---------------- row softmax in-place, W = 16384 (64 floats/thread) --------
__global__ __launch_bounds__(256) void k_softmax(
    float* __restrict__ S, float scale) {
    float* sr = S + (long long)blockIdx.x * 16384;
    float4 r[16];
    float mx = -1e30f;
#pragma unroll
    for (int i = 0; i < 16; ++i) {
        float4 t = ((const float4*)sr)[threadIdx.x + (i << 8)];
        t.x *= scale; t.y *= scale; t.z *= scale; t.w *= scale;
        r[i] = t;
        mx = fmaxf(mx, fmaxf(fmaxf(t.x, t.y), fmaxf(t.z, t.w)));
    }
    mx = blk_max(mx);
    float sum = 0.f;
#pragma unroll
    for (int i = 0; i < 16; ++i) {
        float4 t = r[i];
        t.x = __expf(t.x - mx); t.y = __expf(t.y - mx);
        t.z = __expf(t.z - mx); t.w = __expf(t.w - mx);
        r[i] = t;
        sum += t.x + t.y + t.z + t.w;
    }
    sum = blk_sum(sum);
    float inv = 1.0f / sum;
#pragma unroll
    for (int i = 0; i < 16; ++i) {
        float4 t = r[i];
        t.x *= inv; t.y *= inv; t.z *= inv; t.w *= inv;
        ((float4*)sr)[threadIdx.x + (i << 8)] = t;
    }
}

extern "C" void kernel_launch(void* const* d_in, const int* in_sizes, int n_in,
                              void* d_out, int out_size, void* d_ws, size_t ws_size,
                              hipStream_t stream) {
    const float* x      = (const float*)d_in[0];
    const float* X_data = (const float*)d_in[1];
    const int*   midx   = (const int*)d_in[2];
    const float* W_q    = (const float*)d_in[3];
    const float* W_k    = (const float*)d_in[4];
    const float* W_v    = (const float*)d_in[5];
    const float* g_q    = (const float*)d_in[6];
    const float* b_q    = (const float*)d_in[7];
    const float* g_k    = (const float*)d_in[8];
    const float* b_k    = (const float*)d_in[9];
    const float* g_v    = (const float*)d_in[10];
    const float* b_v    = (const float*)d_in[11];

    const int n  = in_sizes[10];        // 1024
    const int a  = in_sizes[6];         // 256
    const int m  = in_sizes[2];         // 16384
    const int Bn = in_sizes[0] / n;     // 4096

    // output layout: xs | x_hat | attn | v
    float* out  = (float*)d_out;
    float* xs   = out;
    float* xhat = xs + (long long)Bn * n;
    float* attn = xhat + (long long)Bn * n;
    float* vout = attn + (long long)Bn * m;

    // workspace: norms[m] | cinv[1](+pad) | q[Bn*a] | k[m*a]  (~21 MB)
    float* ws    = (float*)d_ws;
    float* norms = ws;
    float* cinv  = ws + m;
    float* qmat  = ws + m + 4;
    float* kmat  = qmat + (long long)Bn * a;

    // 1) C normalizer (deterministic two-stage reduction, no atomics)
    hipLaunchKernelGGL(k_row_norms, dim3(m), dim3(256), 0, stream,
                       X_data, midx, norms, n);
    hipLaunchKernelGGL(k_cinv, dim3(1), dim3(256), 0, stream, norms, m, n, cinv);

    // 2) xs = x / C  (output 0)
    hipLaunchKernelGGL(k_scale, dim3(2048), dim3(256), 0, stream,
                       x, cinv, xs, (long long)Bn * n / 4);

    // 3) projections (gather + 1/C folded into A loads for k,v)
    hipLaunchKernelGGL(k_gemm_nt, dim3(Bn / BM, a / BN), dim3(256), 0, stream,
                       xs, n, W_q, n, qmat, a, n, (const int*)nullptr, (const float*)nullptr);
    hipLaunchKernelGGL(k_gemm_nt, dim3(m / BM, a / BN), dim3(256), 0, stream,
                       X_data, n, W_k, n, kmat, a, n, midx, cinv);
    hipLaunchKernelGGL(k_gemm_nt, dim3(m / BM, n / BN), dim3(256), 0, stream,
                       X_data, n, W_v, n, vout, n, n, midx, cinv);

    // 4) per-stream LayerNorms
    hipLaunchKernelGGL(k_layernorm<1>, dim3(Bn), dim3(256), 0, stream, qmat, g_q, b_q, a);
    hipLaunchKernelGGL(k_layernorm<1>, dim3(m),  dim3(256), 0, stream, kmat, g_k, b_k, a);
    hipLaunchKernelGGL(k_layernorm<4>, dim3(m),  dim3(256), 0, stream, vout, g_v, b_v, n);

    // 5) attention logits S = q k^T (output 2, pre-softmax), then softmax
    hipLaunchKernelGGL(k_gemm_nt, dim3(Bn / BM, m / BN), dim3(256), 0, stream,
                       qmat, a, kmat, a, attn, m, a, (const int*)nullptr, (const float*)nullptr);
    float sc = 1.0f / sqrtf((float)a);
    hipLaunchKernelGGL(k_softmax, dim3(Bn), dim3(256), 0, stream, attn, sc);

    // 6) x_hat = attn @ v  (output 1)
    hipLaunchKernelGGL(k_gemm_nn, dim3(Bn / BM, n / BN), dim3(256), 0, stream,
                       attn, m, vout, n, xhat, n, m);
}

// Round 2
// 770.349 us; speedup vs baseline: 4.2829x; 4.2829x over previous
//
#include <hip/hip_runtime.h>
#include <math.h>

typedef _Float16 hlf4 __attribute__((ext_vector_type(4)));
typedef _Float16 hlf8 __attribute__((ext_vector_type(8)));
typedef float f32x4 __attribute__((ext_vector_type(4)));

// ---------------- block reductions (deterministic tree order) ----------------
static __device__ __forceinline__ float blk_sum(float v) {
    __shared__ float sm[256];
    int tid = threadIdx.x;
    sm[tid] = v; __syncthreads();
#pragma unroll
    for (int s = 128; s > 0; s >>= 1) {
        if (tid < s) sm[tid] += sm[tid + s];
        __syncthreads();
    }
    float r = sm[0]; __syncthreads();
    return r;
}

static __device__ __forceinline__ float blk_max(float v) {
    __shared__ float sm[256];
    int tid = threadIdx.x;
    sm[tid] = v; __syncthreads();
#pragma unroll
    for (int s = 128; s > 0; s >>= 1) {
        if (tid < s) sm[tid] = fmaxf(sm[tid], sm[tid + s]);
        __syncthreads();
    }
    float r = sm[0]; __syncthreads();
    return r;
}

// ---------------- C normalizer: per-row norms of gathered rows ----------------
__global__ __launch_bounds__(256) void k_row_norms(
    const float* __restrict__ X, const int* __restrict__ idx,
    float* __restrict__ norms, int n) {
    long long r = idx[blockIdx.x];
    const float* xr = X + r * (long long)n;
    float s = 0.f;
    for (int k = threadIdx.x * 4; k < n; k += 256 * 4) {
        float4 v = *(const float4*)(xr + k);
        s = fmaf(v.x, v.x, s); s = fmaf(v.y, v.y, s);
        s = fmaf(v.z, v.z, s); s = fmaf(v.w, v.w, s);
    }
    float tot = blk_sum(s);
    if (threadIdx.x == 0) norms[blockIdx.x] = sqrtf(tot);
}

__global__ __launch_bounds__(256) void k_cinv(
    const float* __restrict__ norms, int m, int n, float* __restrict__ cinv) {
    float s = 0.f;
    for (int i = threadIdx.x; i < m; i += 256) s += norms[i];
    float tot = blk_sum(s);
    if (threadIdx.x == 0) cinv[0] = (float)m * sqrtf((float)n) / tot;  // 1/C
}

// ---------------- xs = x * (1/C): f32 out + f16 copy ----------------
__global__ __launch_bounds__(256) void k_scale2(
    const float* __restrict__ x, const float* __restrict__ cinv,
    float* __restrict__ y, _Float16* __restrict__ yh, long long total4) {
    float c = cinv[0];
    long long i = blockIdx.x * 256ll + threadIdx.x;
    long long stride = (long long)gridDim.x * 256ll;
    for (; i < total4; i += stride) {
        float4 v = ((const float4*)x)[i];
        v.x *= c; v.y *= c; v.z *= c; v.w *= c;
        ((float4*)y)[i] = v;
        hlf4 o = {(_Float16)v.x, (_Float16)v.y, (_Float16)v.z, (_Float16)v.w};
        ((hlf4*)yh)[i] = o;
    }
}

// ---------------- gather + scale + cvt: Xc_h[r] = f16(X[idx[r]] * cinv) ------
__global__ __launch_bounds__(256) void k_gather_cvt(
    const float* __restrict__ X, const int* __restrict__ idx,
    const float* __restrict__ cinv, _Float16* __restrict__ out, int n) {
    long long r = idx[blockIdx.x];
    float c = cinv[0];
    const float* src = X + r * (long long)n;
    _Float16* dst = out + (long long)blockIdx.x * n;
    for (int k = threadIdx.x * 4; k < n; k += 256 * 4) {
        float4 v = *(const float4*)(src + k);
        hlf4 o = {(_Float16)(v.x * c), (_Float16)(v.y * c),
                  (_Float16)(v.z * c), (_Float16)(v.w * c)};
        *(hlf4*)(dst + k) = o;
    }
}

// ---------------- flat f32 -> f16 ----------------
__global__ __launch_bounds__(256) void k_cvt(
    const float* __restrict__ in, _Float16* __restrict__ out, long long n4) {
    long long i = blockIdx.x * 256ll + threadIdx.x;
    long long stride = (long long)gridDim.x * 256ll;
    for (; i < n4; i += stride) {
        float4 v = ((const float4*)in)[i];
        hlf4 o = {(_Float16)v.x, (_Float16)v.y, (_Float16)v.z, (_Float16)v.w};
        ((hlf4*)out)[i] = o;
    }
}

// ---------------- transpose + cvt: in[R][Cc] f32 -> out[Cc][R] f16 ----------
__global__ __launch_bounds__(256) void k_tcvt(
    const float* __restrict__ in, _Float16* __restrict__ out, int R, int Cc) {
    __shared__ _Float16 t[32][34];
    int tx = threadIdx.x & 31, ty = threadIdx.x >> 5;   // ty 0..7
    int c0 = blockIdx.x * 32, r0 = blockIdx.y * 32;
#pragma unroll
    for (int i = 0; i < 32; i += 8)
        t[ty + i][tx] = (_Float16)in[(long long)(r0 + ty + i) * Cc + c0 + tx];
    __syncthreads();
#pragma unroll
    for (int i = 0; i < 32; i += 8)
        out[(long long)(c0 + ty + i) * R + r0 + tx] = t[tx][ty + i];
}

// ---------------- load 16 elems (cvt if f32) into f16 regs ----------------
template <typename T>
static __device__ __forceinline__ void ld16(_Float16* dst, const T* p) {
    if constexpr (sizeof(T) == 4) {
        float4 a = *(const float4*)(p + 0), b = *(const float4*)(p + 4);
        float4 c = *(const float4*)(p + 8), d = *(const float4*)(p + 12);
        dst[0] = (_Float16)a.x; dst[1] = (_Float16)a.y; dst[2] = (_Float16)a.z; dst[3] = (_Float16)a.w;
        dst[4] = (_Float16)b.x; dst[5] = (_Float16)b.y; dst[6] = (_Float16)b.z; dst[7] = (_Float16)b.w;
        dst[8] = (_Float16)c.x; dst[9] = (_Float16)c.y; dst[10] = (_Float16)c.z; dst[11] = (_Float16)c.w;
        dst[12] = (_Float16)d.x; dst[13] = (_Float16)d.y; dst[14] = (_Float16)d.z; dst[15] = (_Float16)d.w;
    } else {
        *(float4*)(dst + 0) = *(const float4*)(p + 0);
        *(float4*)(dst + 8) = *(const float4*)(p + 8);
    }
}

// ---------------- MFMA NT GEMM: C[i][j] = sum_k A[i][k]*B[j][k] -------------
// 128x128 tile, BK=32, 4 waves (2x2), 4x4 16x16x32 frags/wave.
// LDS rows padded to 40 halfs (80 B) -> frag b128 reads are 2-way on banks (free).
#define GLDH 40
template <typename TA, typename TB>
__global__ __launch_bounds__(256, 2) void k_gemm16(
    const TA* __restrict__ A, int lda,
    const TB* __restrict__ B, int ldb,
    float* __restrict__ C, int ldc, int K) {
    __shared__ _Float16 Ah[2][128 * GLDH];
    __shared__ _Float16 Bh[2][128 * GLDH];
    const int tid = threadIdx.x;
    const long long m0 = (long long)blockIdx.x * 128;
    const long long n0 = (long long)blockIdx.y * 128;
    const int srow = tid >> 1, sseg = tid & 1;
    const TA* Ap = A + (m0 + srow) * lda + sseg * 16;
    const TB* Bp = B + (n0 + srow) * ldb + sseg * 16;
    const int lane = tid & 63, wv = tid >> 6;
    const int wm = (wv >> 1) * 64, wn = (wv & 1) * 64;
    const int fr = lane & 15, fq = lane >> 4;
    const int sOff = srow * GLDH + sseg * 16;

    f32x4 acc[4][4] = {};
    alignas(16) _Float16 ra[16], rb[16];

    // prologue: stage tile 0 into buf 0
    ld16(ra, Ap); ld16(rb, Bp);
    *(hlf8*)&Ah[0][sOff] = *(hlf8*)&ra[0]; *(hlf8*)&Ah[0][sOff + 8] = *(hlf8*)&ra[8];
    *(hlf8*)&Bh[0][sOff] = *(hlf8*)&rb[0]; *(hlf8*)&Bh[0][sOff + 8] = *(hlf8*)&rb[8];
    __syncthreads();

    const int NT = K / 32;
    for (int kt = 0; kt < NT; ++kt) {
        const int cur = kt & 1;
        if (kt + 1 < NT) {
            ld16(ra, Ap + (long long)(kt + 1) * 32);
            ld16(rb, Bp + (long long)(kt + 1) * 32);
        }
        hlf8 af[4], bf[4];
#pragma unroll
        for (int i = 0; i < 4; ++i) {
            af[i] = *(const hlf8*)&Ah[cur][(wm + i * 16 + fr) * GLDH + fq * 8];
            bf[i] = *(const hlf8*)&Bh[cur][(wn + i * 16 + fr) * GLDH + fq * 8];
        }
#pragma unroll
        for (int i = 0; i < 4; ++i)
#pragma unroll
            for (int j = 0; j < 4; ++j)
                acc[i][j] = __builtin_amdgcn_mfma_f32_16x16x32_f16(af[i], bf[j], acc[i][j], 0, 0, 0);
        if (kt + 1 < NT) {
            const int nx = cur ^ 1;
            *(hlf8*)&Ah[nx][sOff] = *(hlf8*)&ra[0]; *(hlf8*)&Ah[nx][sOff + 8] = *(hlf8*)&ra[8];
            *(hlf8*)&Bh[nx][sOff] = *(hlf8*)&rb[0]; *(hlf8*)&Bh[nx][sOff + 8] = *(hlf8*)&rb[8];
        }
        __syncthreads();
    }

    // epilogue: C/D layout col=lane&15, row=(lane>>4)*4+reg (m89-verified)
#pragma unroll
    for (int i = 0; i < 4; ++i)
#pragma unroll
        for (int j = 0; j < 4; ++j) {
            float* cp = C + (m0 + wm + i * 16 + fq * 4) * ldc + (n0 + wn + j * 16 + fr);
#pragma unroll
            for (int r = 0; r < 4; ++r) cp[(long long)r * ldc] = acc[i][j][r];
        }
}

// ---------------- row LayerNorm in-place, width W = CNT*256 ----------------
template <int CNT>
__global__ __launch_bounds__(256) void k_layernorm(
    float* __restrict__ Y, const float* __restrict__ g,
    const float* __restrict__ b, int W) {
    float* yr = Y + (long long)blockIdx.x * W;
    float v[CNT];
    float s = 0.f;
#pragma unroll
    for (int i = 0; i < CNT; ++i) {
        v[i] = yr[threadIdx.x + (i << 8)];
        s += v[i];
    }
    float mu = blk_sum(s) / (float)W;
    float sq = 0.f;
#pragma unroll
    for (int i = 0; i < CNT; ++i) {
        float d = v[i] - mu;
        sq = fmaf(d, d, sq);
    }
    float var = blk_sum(sq) / (float)W;
    float rs = rsqrtf(var + 1e-5f);
#pragma unroll
    for (int i = 0; i < CNT; ++i) {
        int col = threadIdx.x + (i << 8);
        yr[col] = (v[i] - mu) * rs * g[col] + b[col];
    }
}

// -------- row softmax in-place, W = 16384; optional f16 copy of result ------
__global__ __launch_bounds__(256) void k_softmax(
    float* __restrict__ S, _Float16* __restrict__ Sh, float scale) {
    float* sr = S + (long long)blockIdx.x * 16384;
    _Float16* shr = Sh ? Sh + (long long)blockIdx.x * 16384 : nullptr;
    float4 r[16];
    float mx = -1e30f;
#pragma unroll
    for (int i = 0; i < 16; ++i) {
        float4 t = ((const float4*)sr)[threadIdx.x + (i << 8)];
        t.x *= scale; t.y *= scale; t.z *= scale; t.w *= scale;
        r[i] = t;
        mx = fmaxf(mx, fmaxf(fmaxf(t.x, t.y), fmaxf(t.z, t.w)));
    }
    mx = blk_max(mx);
    float sum = 0.f;
#pragma unroll
    for (int i = 0; i < 16; ++i) {
        float4 t = r[i];
        t.x = __expf(t.x - mx); t.y = __expf(t.y - mx);
        t.z = __expf(t.z - mx); t.w = __expf(t.w - mx);
        r[i] = t;
        sum += t.x + t.y + t.z + t.w;
    }
    sum = blk_sum(sum);
    float inv = 1.0f / sum;
#pragma unroll
    for (int i = 0; i < 16; ++i) {
        float4 t = r[i];
        t.x *= inv; t.y *= inv; t.z *= inv; t.w *= inv;
        ((float4*)sr)[threadIdx.x + (i << 8)] = t;
        if (shr) {
            hlf4 o = {(_Float16)t.x, (_Float16)t.y, (_Float16)t.z, (_Float16)t.w};
            ((hlf4*)shr)[threadIdx.x + (i << 8)] = o;
        }
    }
}

extern "C" void kernel_launch(void* const* d_in, const int* in_sizes, int n_in,
                              void* d_out, int out_size, void* d_ws, size_t ws_size,
                              hipStream_t stream) {
    const float* x      = (const float*)d_in[0];
    const float* X_data = (const float*)d_in[1];
    const int*   midx   = (const int*)d_in[2];
    const float* W_q    = (const float*)d_in[3];
    const float* W_k    = (const float*)d_in[4];
    const float* W_v    = (const float*)d_in[5];
    const float* g_q    = (const float*)d_in[6];
    const float* b_q    = (const float*)d_in[7];
    const float* g_k    = (const float*)d_in[8];
    const float* b_k    = (const float*)d_in[9];
    const float* g_v    = (const float*)d_in[10];
    const float* b_v    = (const float*)d_in[11];

    const int n  = in_sizes[10];        // 1024
    const int a  = in_sizes[6];         // 256
    const int m  = in_sizes[2];         // 16384
    const int Bn = in_sizes[0] / n;     // 4096

    // output layout: xs | x_hat | attn | v
    float* out  = (float*)d_out;
    float* xs   = out;
    float* xhat = xs + (long long)Bn * n;
    float* attn = xhat + (long long)Bn * n;
    float* vout = attn + (long long)Bn * m;

    // workspace carving (256B aligned regions)
    char* wp = (char*)d_ws;
    auto carve = [&](size_t bytes) -> char* {
        char* r = wp; wp += (bytes + 255) & ~(size_t)255; return r;
    };
    float*     norms = (float*)carve((size_t)m * 4);
    float*     cinv  = (float*)carve(16);
    float*     qmat  = (float*)carve((size_t)Bn * a * 4);
    float*     kmat  = (float*)carve((size_t)m * a * 4);
    _Float16*  xs_h  = (_Float16*)carve((size_t)Bn * n * 2);
    _Float16*  Xc_h  = (_Float16*)carve((size_t)m * n * 2);
    _Float16*  Wq_h  = (_Float16*)carve((size_t)a * n * 2);
    _Float16*  Wk_h  = (_Float16*)carve((size_t)a * n * 2);
    _Float16*  Wv_h  = (_Float16*)carve((size_t)n * n * 2);
    _Float16*  q_h   = (_Float16*)carve((size_t)Bn * a * 2);
    _Float16*  k_h   = (_Float16*)carve((size_t)m * a * 2);
    _Float16*  vT_h  = (_Float16*)carve((size_t)n * m * 2);
    size_t used = (size_t)(wp - (char*)d_ws);
    _Float16* attn_h = nullptr;
    if (ws_size >= used + (size_t)Bn * m * 2 + 256)
        attn_h = (_Float16*)carve((size_t)Bn * m * 2);

    // 1) C normalizer
    hipLaunchKernelGGL(k_row_norms, dim3(m), dim3(256), 0, stream, X_data, midx, norms, n);
    hipLaunchKernelGGL(k_cinv, dim3(1), dim3(256), 0, stream, norms, m, n, cinv);

    // 2) xs = x/C (f32 output + f16 copy); gathered+scaled Xc in f16
    hipLaunchKernelGGL(k_scale2, dim3(2048), dim3(256), 0, stream,
                       x, cinv, xs, xs_h, (long long)Bn * n / 4);
    hipLaunchKernelGGL(k_gather_cvt, dim3(m), dim3(256), 0, stream,
                       X_data, midx, cinv, Xc_h, n);

    // 3) weights -> f16
    hipLaunchKernelGGL(k_cvt, dim3(256), dim3(256), 0, stream, W_q, Wq_h, (long long)a * n / 4);
    hipLaunchKernelGGL(k_cvt, dim3(256), dim3(256), 0, stream, W_k, Wk_h, (long long)a * n / 4);
    hipLaunchKernelGGL(k_cvt, dim3(1024), dim3(256), 0, stream, W_v, Wv_h, (long long)n * n / 4);

    // 4) projections (MFMA f16, fp32 accum)
    hipLaunchKernelGGL((k_gemm16<_Float16, _Float16>), dim3(Bn / 128, a / 128), dim3(256), 0, stream,
                       xs_h, n, Wq_h, n, qmat, a, n);
    hipLaunchKernelGGL((k_gemm16<_Float16, _Float16>), dim3(m / 128, a / 128), dim3(256), 0, stream,
                       Xc_h, n, Wk_h, n, kmat, a, n);
    hipLaunchKernelGGL((k_gemm16<_Float16, _Float16>), dim3(m / 128, n / 128), dim3(256), 0, stream,
                       Xc_h, n, Wv_h, n, vout, n, n);

    // 5) LayerNorms (f32) + f16 copies of q,k and transposed v
    hipLaunchKernelGGL(k_layernorm<1>, dim3(Bn), dim3(256), 0, stream, qmat, g_q, b_q, a);
    hipLaunchKernelGGL(k_layernorm<1>, dim3(m),  dim3(256), 0, stream, kmat, g_k, b_k, a);
    hipLaunchKernelGGL(k_layernorm<4>, dim3(m),  dim3(256), 0, stream, vout, g_v, b_v, n);
    hipLaunchKernelGGL(k_cvt, dim3(1024), dim3(256), 0, stream, qmat, q_h, (long long)Bn * a / 4);
    hipLaunchKernelGGL(k_cvt, dim3(4096), dim3(256), 0, stream, kmat, k_h, (long long)m * a / 4);
    hipLaunchKernelGGL(k_tcvt, dim3(n / 32, m / 32), dim3(256), 0, stream, vout, vT_h, m, n);

    // 6) S = q k^T (f32 logits into attn buffer), softmax in place (+f16 copy)
    hipLaunchKernelGGL((k_gemm16<_Float16, _Float16>), dim3(Bn / 128, m / 128), dim3(256), 0, stream,
                       q_h, a, k_h, a, attn, m, a);
    float sc = 1.0f / sqrtf((float)a);
    hipLaunchKernelGGL(k_softmax, dim3(Bn), dim3(256), 0, stream, attn, attn_h, sc);

    // 7) x_hat = attn @ v  (vT_h is [n][m] f16; A is f16 copy if ws allowed, else f32)
    if (attn_h)
        hipLaunchKernelGGL((k_gemm16<_Float16, _Float16>), dim3(Bn / 128, n / 128), dim3(256), 0, stream,
                           attn_h, m, vT_h, m, xhat, n, m);
    else
        hipLaunchKernelGGL((k_gemm16<float, _Float16>), dim3(Bn / 128, n / 128), dim3(256), 0, stream,
                           attn, m, vT_h, m, xhat, n, m);
}

// Round 3
// 669.334 us; speedup vs baseline: 4.9293x; 1.1509x over previous
//
#include <hip/hip_runtime.h>
#include <math.h>

typedef _Float16 hlf4 __attribute__((ext_vector_type(4)));
typedef _Float16 hlf8 __attribute__((ext_vector_type(8)));
typedef float f32x4 __attribute__((ext_vector_type(4)));

// ---------------- block reductions (deterministic tree order) ----------------
static __device__ __forceinline__ float blk_sum(float v) {
    __shared__ float sm[256];
    int tid = threadIdx.x;
    sm[tid] = v; __syncthreads();
#pragma unroll
    for (int s = 128; s > 0; s >>= 1) {
        if (tid < s) sm[tid] += sm[tid + s];
        __syncthreads();
    }
    float r = sm[0]; __syncthreads();
    return r;
}

static __device__ __forceinline__ float blk_max(float v) {
    __shared__ float sm[256];
    int tid = threadIdx.x;
    sm[tid] = v; __syncthreads();
#pragma unroll
    for (int s = 128; s > 0; s >>= 1) {
        if (tid < s) sm[tid] = fmaxf(sm[tid], sm[tid + s]);
        __syncthreads();
    }
    float r = sm[0]; __syncthreads();
    return r;
}

// ---------------- C normalizer: per-row norms of gathered rows ----------------
__global__ __launch_bounds__(256) void k_row_norms(
    const float* __restrict__ X, const int* __restrict__ idx,
    float* __restrict__ norms, int n) {
    long long r = idx[blockIdx.x];
    const float* xr = X + r * (long long)n;
    float s = 0.f;
    for (int k = threadIdx.x * 4; k < n; k += 256 * 4) {
        float4 v = *(const float4*)(xr + k);
        s = fmaf(v.x, v.x, s); s = fmaf(v.y, v.y, s);
        s = fmaf(v.z, v.z, s); s = fmaf(v.w, v.w, s);
    }
    float tot = blk_sum(s);
    if (threadIdx.x == 0) norms[blockIdx.x] = sqrtf(tot);
}

__global__ __launch_bounds__(256) void k_cinv(
    const float* __restrict__ norms, int m, int n, float* __restrict__ cinv) {
    float s = 0.f;
    for (int i = threadIdx.x; i < m; i += 256) s += norms[i];
    float tot = blk_sum(s);
    if (threadIdx.x == 0) cinv[0] = (float)m * sqrtf((float)n) / tot;  // 1/C
}

// ---------------- xs = x * (1/C): f32 out + f16 copy ----------------
__global__ __launch_bounds__(256) void k_scale2(
    const float* __restrict__ x, const float* __restrict__ cinv,
    float* __restrict__ y, _Float16* __restrict__ yh, long long total4) {
    float c = cinv[0];
    long long i = blockIdx.x * 256ll + threadIdx.x;
    long long stride = (long long)gridDim.x * 256ll;
    for (; i < total4; i += stride) {
        float4 v = ((const float4*)x)[i];
        v.x *= c; v.y *= c; v.z *= c; v.w *= c;
        ((float4*)y)[i] = v;
        hlf4 o = {(_Float16)v.x, (_Float16)v.y, (_Float16)v.z, (_Float16)v.w};
        ((hlf4*)yh)[i] = o;
    }
}

// ---------------- gather + scale + cvt: Xc_h[r] = f16(X[idx[r]] * cinv) ------
__global__ __launch_bounds__(256) void k_gather_cvt(
    const float* __restrict__ X, const int* __restrict__ idx,
    const float* __restrict__ cinv, _Float16* __restrict__ out, int n) {
    long long r = idx[blockIdx.x];
    float c = cinv[0];
    const float* src = X + r * (long long)n;
    _Float16* dst = out + (long long)blockIdx.x * n;
    for (int k = threadIdx.x * 4; k < n; k += 256 * 4) {
        float4 v = *(const float4*)(src + k);
        hlf4 o = {(_Float16)(v.x * c), (_Float16)(v.y * c),
                  (_Float16)(v.z * c), (_Float16)(v.w * c)};
        *(hlf4*)(dst + k) = o;
    }
}

// ---------------- flat f32 -> f16 ----------------
__global__ __launch_bounds__(256) void k_cvt(
    const float* __restrict__ in, _Float16* __restrict__ out, long long n4) {
    long long i = blockIdx.x * 256ll + threadIdx.x;
    long long stride = (long long)gridDim.x * 256ll;
    for (; i < n4; i += stride) {
        float4 v = ((const float4*)in)[i];
        hlf4 o = {(_Float16)v.x, (_Float16)v.y, (_Float16)v.z, (_Float16)v.w};
        ((hlf4*)out)[i] = o;
    }
}

// ---------------- transpose + cvt: in[R][Cc] f32 -> out[Cc][R] f16 ----------
__global__ __launch_bounds__(256) void k_tcvt(
    const float* __restrict__ in, _Float16* __restrict__ out, int R, int Cc) {
    __shared__ _Float16 t[32][34];
    int tx = threadIdx.x & 31, ty = threadIdx.x >> 5;   // ty 0..7
    int c0 = blockIdx.x * 32, r0 = blockIdx.y * 32;
#pragma unroll
    for (int i = 0; i < 32; i += 8)
        t[ty + i][tx] = (_Float16)in[(long long)(r0 + ty + i) * Cc + c0 + tx];
    __syncthreads();
#pragma unroll
    for (int i = 0; i < 32; i += 8)
        out[(long long)(c0 + ty + i) * R + r0 + tx] = t[tx][ty + i];
}

// ---------------- load 8 elems (cvt if f32) into one hlf8 ----------------
template <typename T>
static __device__ __forceinline__ hlf8 ld8(const T* p) {
    if constexpr (sizeof(T) == 4) {
        float4 a = *(const float4*)(p + 0);
        float4 b = *(const float4*)(p + 4);
        hlf8 r = {(_Float16)a.x, (_Float16)a.y, (_Float16)a.z, (_Float16)a.w,
                  (_Float16)b.x, (_Float16)b.y, (_Float16)b.z, (_Float16)b.w};
        return r;
    } else {
        return *(const hlf8*)p;
    }
}

// ---------------- MFMA NT GEMM, 8 waves, optional split-K -------------------
// C[i][j] = sum_k A[i][k]*B[j][k].  128x128 tile, BK=32, dbuf LDS, 512 thr.
// Waves: 2(M)x4(N), each 64x32 -> 4x2 frags of 16x16x32.
// LDS rows padded to 40 halfs (80 B): 16B-slot-uniform for frag reads+writes.
// gridDim.z > 1: block z covers K-chunk [z*K/Z,...), writes f32 partial at
// part + z*zstride; else writes C directly.
#define GLDH 40
template <typename TA, typename TB>
__global__ __launch_bounds__(512) void k_gemm8(
    const TA* __restrict__ A, int lda,
    const TB* __restrict__ B, int ldb,
    float* __restrict__ Cc, long long ldc, int K,
    float* __restrict__ part, long long zstride) {
    __shared__ _Float16 Ah[2][128 * GLDH];
    __shared__ _Float16 Bh[2][128 * GLDH];
    const int tid = threadIdx.x;
    const long long m0 = (long long)blockIdx.x * 128;
    const long long n0 = (long long)blockIdx.y * 128;
    const int KC = K / gridDim.z;
    const int kbase = blockIdx.z * KC;
    const int srow = tid >> 2, sseg = tid & 3;        // 128 rows x 4 segs x 8 halfs
    const TA* Ap = A + (m0 + srow) * lda + kbase + sseg * 8;
    const TB* Bp = B + (n0 + srow) * ldb + kbase + sseg * 8;
    const int lane = tid & 63, wv = tid >> 6;
    const int wm = (wv >> 2) * 64, wn = (wv & 3) * 32;
    const int fr = lane & 15, fq = lane >> 4;
    const int sOff = srow * GLDH + sseg * 8;

    f32x4 acc[4][2] = {};
    hlf8 ra, rb;

    ra = ld8(Ap); rb = ld8(Bp);
    *(hlf8*)&Ah[0][sOff] = ra; *(hlf8*)&Bh[0][sOff] = rb;
    __syncthreads();

    const int NT = KC / 32;
    for (int kt = 0; kt < NT; ++kt) {
        const int cur = kt & 1;
        if (kt + 1 < NT) {
            ra = ld8(Ap + (long long)(kt + 1) * 32);
            rb = ld8(Bp + (long long)(kt + 1) * 32);
        }
        hlf8 af[4], bf[2];
#pragma unroll
        for (int i = 0; i < 4; ++i)
            af[i] = *(const hlf8*)&Ah[cur][(wm + i * 16 + fr) * GLDH + fq * 8];
#pragma unroll
        for (int j = 0; j < 2; ++j)
            bf[j] = *(const hlf8*)&Bh[cur][(wn + j * 16 + fr) * GLDH + fq * 8];
#pragma unroll
        for (int i = 0; i < 4; ++i)
#pragma unroll
            for (int j = 0; j < 2; ++j)
                acc[i][j] = __builtin_amdgcn_mfma_f32_16x16x32_f16(af[i], bf[j], acc[i][j], 0, 0, 0);
        if (kt + 1 < NT) {
            const int nx = cur ^ 1;
            *(hlf8*)&Ah[nx][sOff] = ra; *(hlf8*)&Bh[nx][sOff] = rb;
        }
        __syncthreads();
    }

    float* out = (gridDim.z == 1) ? Cc : (part + (long long)blockIdx.z * zstride);
    // C/D layout: col=lane&15, row=(lane>>4)*4+reg (m89-verified)
#pragma unroll
    for (int i = 0; i < 4; ++i)
#pragma unroll
        for (int j = 0; j < 2; ++j) {
            float* cp = out + (m0 + wm + i * 16 + fq * 4) * ldc + (n0 + wn + j * 16 + fr);
#pragma unroll
            for (int r = 0; r < 4; ++r) cp[(long long)r * ldc] = acc[i][j][r];
        }
}

// ---------------- split-K reduction: out = sum_z part[z] ----------------
__global__ __launch_bounds__(256) void k_redux(
    const float* __restrict__ part, float* __restrict__ out,
    long long n4, long long zs4, int Z) {
    long long i = blockIdx.x * 256ll + threadIdx.x;
    long long stride = (long long)gridDim.x * 256ll;
    for (; i < n4; i += stride) {
        float4 s = ((const float4*)part)[i];
        for (int z = 1; z < Z; ++z) {
            float4 t = ((const float4*)part)[i + z * zs4];
            s.x += t.x; s.y += t.y; s.z += t.z; s.w += t.w;
        }
        ((float4*)out)[i] = s;
    }
}

// ---------------- row LayerNorm in-place, width W = CNT*256 ----------------
template <int CNT>
__global__ __launch_bounds__(256) void k_layernorm(
    float* __restrict__ Y, const float* __restrict__ g,
    const float* __restrict__ b, int W) {
    float* yr = Y + (long long)blockIdx.x * W;
    float v[CNT];
    float s = 0.f;
#pragma unroll
    for (int i = 0; i < CNT; ++i) {
        v[i] = yr[threadIdx.x + (i << 8)];
        s += v[i];
    }
    float mu = blk_sum(s) / (float)W;
    float sq = 0.f;
#pragma unroll
    for (int i = 0; i < CNT; ++i) {
        float d = v[i] - mu;
        sq = fmaf(d, d, sq);
    }
    float var = blk_sum(sq) / (float)W;
    float rs = rsqrtf(var + 1e-5f);
#pragma unroll
    for (int i = 0; i < CNT; ++i) {
        int col = threadIdx.x + (i << 8);
        yr[col] = (v[i] - mu) * rs * g[col] + b[col];
    }
}

// -------- row softmax in-place, W = 16384; optional f16 copy of result ------
__global__ __launch_bounds__(256) void k_softmax(
    float* __restrict__ S, _Float16* __restrict__ Sh, float scale) {
    float* sr = S + (long long)blockIdx.x * 16384;
    _Float16* shr = Sh ? Sh + (long long)blockIdx.x * 16384 : nullptr;
    float4 r[16];
    float mx = -1e30f;
#pragma unroll
    for (int i = 0; i < 16; ++i) {
        float4 t = ((const float4*)sr)[threadIdx.x + (i << 8)];
        t.x *= scale; t.y *= scale; t.z *= scale; t.w *= scale;
        r[i] = t;
        mx = fmaxf(mx, fmaxf(fmaxf(t.x, t.y), fmaxf(t.z, t.w)));
    }
    mx = blk_max(mx);
    float sum = 0.f;
#pragma unroll
    for (int i = 0; i < 16; ++i) {
        float4 t = r[i];
        t.x = __expf(t.x - mx); t.y = __expf(t.y - mx);
        t.z = __expf(t.z - mx); t.w = __expf(t.w - mx);
        r[i] = t;
        sum += t.x + t.y + t.z + t.w;
    }
    sum = blk_sum(sum);
    float inv = 1.0f / sum;
#pragma unroll
    for (int i = 0; i < 16; ++i) {
        float4 t = r[i];
        t.x *= inv; t.y *= inv; t.z *= inv; t.w *= inv;
        ((float4*)sr)[threadIdx.x + (i << 8)] = t;
        if (shr) {
            hlf4 o = {(_Float16)t.x, (_Float16)t.y, (_Float16)t.z, (_Float16)t.w};
            ((hlf4*)shr)[threadIdx.x + (i << 8)] = o;
        }
    }
}

extern "C" void kernel_launch(void* const* d_in, const int* in_sizes, int n_in,
                              void* d_out, int out_size, void* d_ws, size_t ws_size,
                              hipStream_t stream) {
    const float* x      = (const float*)d_in[0];
    const float* X_data = (const float*)d_in[1];
    const int*   midx   = (const int*)d_in[2];
    const float* W_q    = (const float*)d_in[3];
    const float* W_k    = (const float*)d_in[4];
    const float* W_v    = (const float*)d_in[5];
    const float* g_q    = (const float*)d_in[6];
    const float* b_q    = (const float*)d_in[7];
    const float* g_k    = (const float*)d_in[8];
    const float* b_k    = (const float*)d_in[9];
    const float* g_v    = (const float*)d_in[10];
    const float* b_v    = (const float*)d_in[11];

    const int n  = in_sizes[10];        // 1024
    const int a  = in_sizes[6];         // 256
    const int m  = in_sizes[2];         // 16384
    const int Bn = in_sizes[0] / n;     // 4096

    // output layout: xs | x_hat | attn | v
    float* out  = (float*)d_out;
    float* xs   = out;
    float* xhat = xs + (long long)Bn * n;
    float* attn = xhat + (long long)Bn * n;
    float* vout = attn + (long long)Bn * m;

    // workspace carving (256B aligned). The [qmat .. k_h] span (~73 MB) is all
    // dead before the x_hat GEMM runs, so the 64 MB split-K partial buffer
    // aliases it (no extra ws footprint).
    char* wp = (char*)d_ws;
    auto carve = [&](size_t bytes) -> char* {
        char* r = wp; wp += (bytes + 255) & ~(size_t)255; return r;
    };
    float*     norms = (float*)carve((size_t)m * 4);
    float*     cinv  = (float*)carve(16);
    char*      alias0 = wp;                               // split-K partials base
    float*     qmat  = (float*)carve((size_t)Bn * a * 4);
    float*     kmat  = (float*)carve((size_t)m * a * 4);
    _Float16*  xs_h  = (_Float16*)carve((size_t)Bn * n * 2);
    _Float16*  Xc_h  = (_Float16*)carve((size_t)m * n * 2);
    _Float16*  Wq_h  = (_Float16*)carve((size_t)a * n * 2);
    _Float16*  Wk_h  = (_Float16*)carve((size_t)a * n * 2);
    _Float16*  Wv_h  = (_Float16*)carve((size_t)n * n * 2);
    _Float16*  q_h   = (_Float16*)carve((size_t)Bn * a * 2);
    _Float16*  k_h   = (_Float16*)carve((size_t)m * a * 2);
    float*     splitk = (float*)alias0;
    const int  SK = 4;                                    // needs SK*Bn*n*4 <= 73MB
    _Float16*  vT_h  = (_Float16*)carve((size_t)n * m * 2);
    size_t used = (size_t)(wp - (char*)d_ws);
    _Float16* attn_h = nullptr;
    if (ws_size >= used + (size_t)Bn * m * 2 + 256)
        attn_h = (_Float16*)carve((size_t)Bn * m * 2);

    // 1) C normalizer
    hipLaunchKernelGGL(k_row_norms, dim3(m), dim3(256), 0, stream, X_data, midx, norms, n);
    hipLaunchKernelGGL(k_cinv, dim3(1), dim3(256), 0, stream, norms, m, n, cinv);

    // 2) xs = x/C (f32 + f16); gathered+scaled Xc in f16
    hipLaunchKernelGGL(k_scale2, dim3(2048), dim3(256), 0, stream,
                       x, cinv, xs, xs_h, (long long)Bn * n / 4);
    hipLaunchKernelGGL(k_gather_cvt, dim3(m), dim3(256), 0, stream,
                       X_data, midx, cinv, Xc_h, n);

    // 3) weights -> f16
    hipLaunchKernelGGL(k_cvt, dim3(256), dim3(256), 0, stream, W_q, Wq_h, (long long)a * n / 4);
    hipLaunchKernelGGL(k_cvt, dim3(256), dim3(256), 0, stream, W_k, Wk_h, (long long)a * n / 4);
    hipLaunchKernelGGL(k_cvt, dim3(1024), dim3(256), 0, stream, W_v, Wv_h, (long long)n * n / 4);

    // 4) projections (MFMA f16, fp32 accum, 8-wave)
    hipLaunchKernelGGL((k_gemm8<_Float16, _Float16>), dim3(Bn / 128, a / 128), dim3(512), 0, stream,
                       xs_h, n, Wq_h, n, qmat, a, n, (float*)nullptr, 0ll);
    hipLaunchKernelGGL((k_gemm8<_Float16, _Float16>), dim3(m / 128, a / 128), dim3(512), 0, stream,
                       Xc_h, n, Wk_h, n, kmat, a, n, (float*)nullptr, 0ll);
    hipLaunchKernelGGL((k_gemm8<_Float16, _Float16>), dim3(m / 128, n / 128), dim3(512), 0, stream,
                       Xc_h, n, Wv_h, n, vout, n, n, (float*)nullptr, 0ll);

    // 5) LayerNorms (f32) + f16 copies of q,k and transposed v
    hipLaunchKernelGGL(k_layernorm<1>, dim3(Bn), dim3(256), 0, stream, qmat, g_q, b_q, a);
    hipLaunchKernelGGL(k_layernorm<1>, dim3(m),  dim3(256), 0, stream, kmat, g_k, b_k, a);
    hipLaunchKernelGGL(k_layernorm<4>, dim3(m),  dim3(256), 0, stream, vout, g_v, b_v, n);
    hipLaunchKernelGGL(k_cvt, dim3(1024), dim3(256), 0, stream, qmat, q_h, (long long)Bn * a / 4);
    hipLaunchKernelGGL(k_cvt, dim3(4096), dim3(256), 0, stream, kmat, k_h, (long long)m * a / 4);
    hipLaunchKernelGGL(k_tcvt, dim3(n / 32, m / 32), dim3(256), 0, stream, vout, vT_h, m, n);

    // 6) S = q k^T (f32 logits), softmax in place (+f16 copy)
    hipLaunchKernelGGL((k_gemm8<_Float16, _Float16>), dim3(Bn / 128, m / 128), dim3(512), 0, stream,
                       q_h, a, k_h, a, attn, m, a, (float*)nullptr, 0ll);
    float sc = 1.0f / sqrtf((float)a);
    hipLaunchKernelGGL(k_softmax, dim3(Bn), dim3(256), 0, stream, attn, attn_h, sc);

    // 7) x_hat = attn @ v, split-K=4 into aliased partials, then reduce
    long long zstride = (long long)Bn * n;
    if (attn_h)
        hipLaunchKernelGGL((k_gemm8<_Float16, _Float16>), dim3(Bn / 128, n / 128, SK), dim3(512), 0, stream,
                           attn_h, m, vT_h, m, xhat, n, m, splitk, zstride);
    else
        hipLaunchKernelGGL((k_gemm8<float, _Float16>), dim3(Bn / 128, n / 128, SK), dim3(512), 0, stream,
                           attn, m, vT_h, m, xhat, n, m, splitk, zstride);
    hipLaunchKernelGGL(k_redux, dim3(2048), dim3(256), 0, stream,
                       splitk, xhat, (long long)Bn * n / 4, zstride / 4, SK);
}

// Round 4
// 629.274 us; speedup vs baseline: 5.2431x; 1.0637x over previous
//
#include <hip/hip_runtime.h>
#include <math.h>

typedef _Float16 hlf4 __attribute__((ext_vector_type(4)));
typedef _Float16 hlf8 __attribute__((ext_vector_type(8)));
typedef float f32x4 __attribute__((ext_vector_type(4)));

// async global->LDS, 16B per lane; lds base must be wave-uniform
static __device__ __forceinline__ void gl_lds16(const void* g, void* l) {
    __builtin_amdgcn_global_load_lds(
        (const __attribute__((address_space(1))) unsigned int*)g,
        (__attribute__((address_space(3))) unsigned int*)l, 16, 0, 0);
}

// ---------------- block reductions (deterministic tree order) ----------------
static __device__ __forceinline__ float blk_sum(float v) {
    __shared__ float sm[256];
    int tid = threadIdx.x;
    sm[tid] = v; __syncthreads();
#pragma unroll
    for (int s = 128; s > 0; s >>= 1) {
        if (tid < s) sm[tid] += sm[tid + s];
        __syncthreads();
    }
    float r = sm[0]; __syncthreads();
    return r;
}

static __device__ __forceinline__ float blk_max(float v) {
    __shared__ float sm[256];
    int tid = threadIdx.x;
    sm[tid] = v; __syncthreads();
#pragma unroll
    for (int s = 128; s > 0; s >>= 1) {
        if (tid < s) sm[tid] = fmaxf(sm[tid], sm[tid + s]);
        __syncthreads();
    }
    float r = sm[0]; __syncthreads();
    return r;
}

// ---------------- C normalizer: per-row norms of gathered rows ----------------
__global__ __launch_bounds__(256) void k_row_norms(
    const float* __restrict__ X, const int* __restrict__ idx,
    float* __restrict__ norms, int n) {
    long long r = idx[blockIdx.x];
    const float* xr = X + r * (long long)n;
    float s = 0.f;
    for (int k = threadIdx.x * 4; k < n; k += 256 * 4) {
        float4 v = *(const float4*)(xr + k);
        s = fmaf(v.x, v.x, s); s = fmaf(v.y, v.y, s);
        s = fmaf(v.z, v.z, s); s = fmaf(v.w, v.w, s);
    }
    float tot = blk_sum(s);
    if (threadIdx.x == 0) norms[blockIdx.x] = sqrtf(tot);
}

__global__ __launch_bounds__(256) void k_cinv(
    const float* __restrict__ norms, int m, int n, float* __restrict__ cinv) {
    float s = 0.f;
    for (int i = threadIdx.x; i < m; i += 256) s += norms[i];
    float tot = blk_sum(s);
    if (threadIdx.x == 0) cinv[0] = (float)m * sqrtf((float)n) / tot;  // 1/C
}

// ---------------- xs = x * (1/C): f32 out + f16 copy ----------------
__global__ __launch_bounds__(256) void k_scale2(
    const float* __restrict__ x, const float* __restrict__ cinv,
    float* __restrict__ y, _Float16* __restrict__ yh, long long total4) {
    float c = cinv[0];
    long long i = blockIdx.x * 256ll + threadIdx.x;
    long long stride = (long long)gridDim.x * 256ll;
    for (; i < total4; i += stride) {
        float4 v = ((const float4*)x)[i];
        v.x *= c; v.y *= c; v.z *= c; v.w *= c;
        ((float4*)y)[i] = v;
        hlf4 o = {(_Float16)v.x, (_Float16)v.y, (_Float16)v.z, (_Float16)v.w};
        ((hlf4*)yh)[i] = o;
    }
}

// ---------------- gather + scale + cvt: Xc_h[r] = f16(X[idx[r]] * cinv) ------
__global__ __launch_bounds__(256) void k_gather_cvt(
    const float* __restrict__ X, const int* __restrict__ idx,
    const float* __restrict__ cinv, _Float16* __restrict__ out, int n) {
    long long r = idx[blockIdx.x];
    float c = cinv[0];
    const float* src = X + r * (long long)n;
    _Float16* dst = out + (long long)blockIdx.x * n;
    for (int k = threadIdx.x * 4; k < n; k += 256 * 4) {
        float4 v = *(const float4*)(src + k);
        hlf4 o = {(_Float16)(v.x * c), (_Float16)(v.y * c),
                  (_Float16)(v.z * c), (_Float16)(v.w * c)};
        *(hlf4*)(dst + k) = o;
    }
}

// ---------------- flat f32 -> f16 ----------------
__global__ __launch_bounds__(256) void k_cvt(
    const float* __restrict__ in, _Float16* __restrict__ out, long long n4) {
    long long i = blockIdx.x * 256ll + threadIdx.x;
    long long stride = (long long)gridDim.x * 256ll;
    for (; i < n4; i += stride) {
        float4 v = ((const float4*)in)[i];
        hlf4 o = {(_Float16)v.x, (_Float16)v.y, (_Float16)v.z, (_Float16)v.w};
        ((hlf4*)out)[i] = o;
    }
}

// ---------------- transpose + cvt: in[R][Cc] f32 -> out[Cc][R] f16 ----------
__global__ __launch_bounds__(256) void k_tcvt(
    const float* __restrict__ in, _Float16* __restrict__ out, int R, int Cc) {
    __shared__ _Float16 t[32][34];
    int tx = threadIdx.x & 31, ty = threadIdx.x >> 5;   // ty 0..7
    int c0 = blockIdx.x * 32, r0 = blockIdx.y * 32;
#pragma unroll
    for (int i = 0; i < 32; i += 8)
        t[ty + i][tx] = (_Float16)in[(long long)(r0 + ty + i) * Cc + c0 + tx];
    __syncthreads();
#pragma unroll
    for (int i = 0; i < 32; i += 8)
        out[(long long)(c0 + ty + i) * R + r0 + tx] = t[tx][ty + i];
}

// ================= m97-structure MFMA NT GEMM (f16 x f16) ===================
// C[i][j] = sum_k A[i][k]*B[j][k].  128x128 tile, BK=32, 256 thr / 4 waves
// (2Mx2N, 64x64 each, 4x4 frags of 16x16x32), double-buffered linear LDS
// [128][32]h staged via global_load_lds (16B/lane). Bank fix per rule 21:
// pre-swizzled GLOBAL source (seg^=row&3 on 16B segs) + same XOR on frag
// reads -> 2-way (free) instead of 8-way.
// gridDim.z>1: K split; partial f32 written to part + z*zstride.
__global__ __launch_bounds__(256) void k_gemm4(
    const _Float16* __restrict__ A, int lda,
    const _Float16* __restrict__ B, int ldb,
    float* __restrict__ Cc, long long ldc, int K,
    float* __restrict__ part, long long zstride) {
    __shared__ _Float16 Ah[2][4096];
    __shared__ _Float16 Bh[2][4096];
    const int tid = threadIdx.x;
    const long long m0 = (long long)blockIdx.x * 128;
    const long long n0 = (long long)blockIdx.y * 128;
    const int KC = K / gridDim.z;
    const int kbase = blockIdx.z * KC;
    const int lane = tid & 63, wv = tid >> 6;
    const int wm = (wv >> 1) * 64, wn = (wv & 1) * 64;
    const int fr = lane & 15, fq = lane >> 4;

    // staging: 512 16B-slots per matrix tile; thread covers slots tid, tid+256.
    // slot s -> LDS bytes [s*16, s*16+16) = row s>>2, phys seg s&3;
    // global source seg = (s&3) ^ (row&3)  (inverse swizzle).
    const int s0 = tid, s1 = tid + 256;
    const int r0s = s0 >> 2, r1s = s1 >> 2;
    const int g0 = (((s0 & 3) ^ (r0s & 3)) << 3);
    const int g1 = (((s1 & 3) ^ (r1s & 3)) << 3);
    const _Float16* A0 = A + (m0 + r0s) * (long long)lda + kbase + g0;
    const _Float16* A1 = A + (m0 + r1s) * (long long)lda + kbase + g1;
    const _Float16* B0 = B + (n0 + r0s) * (long long)ldb + kbase + g0;
    const _Float16* B1 = B + (n0 + r1s) * (long long)ldb + kbase + g1;

    f32x4 acc[4][4] = {};

    const int NT = KC / 32;
    // prologue: stage tile 0 into buf 0
    {
        gl_lds16(A0, &Ah[0][wv * 512]);
        gl_lds16(A1, &Ah[0][2048 + wv * 512]);
        gl_lds16(B0, &Bh[0][wv * 512]);
        gl_lds16(B1, &Bh[0][2048 + wv * 512]);
    }
    __syncthreads();

    for (int kt = 0; kt < NT; ++kt) {
        const int cur = kt & 1;
        if (kt + 1 < NT) {
            const int nx = cur ^ 1;
            const long long ko = (long long)(kt + 1) * 32;
            gl_lds16(A0 + ko, &Ah[nx][wv * 512]);
            gl_lds16(A1 + ko, &Ah[nx][2048 + wv * 512]);
            gl_lds16(B0 + ko, &Bh[nx][wv * 512]);
            gl_lds16(B1 + ko, &Bh[nx][2048 + wv * 512]);
        }
        hlf8 af[4], bf[4];
#pragma unroll
        for (int i = 0; i < 4; ++i) {
            const int r = wm + i * 16 + fr;
            af[i] = *(const hlf8*)&Ah[cur][r * 32 + ((fq ^ (r & 3)) << 3)];
        }
#pragma unroll
        for (int j = 0; j < 4; ++j) {
            const int r = wn + j * 16 + fr;
            bf[j] = *(const hlf8*)&Bh[cur][r * 32 + ((fq ^ (r & 3)) << 3)];
        }
#pragma unroll
        for (int i = 0; i < 4; ++i)
#pragma unroll
            for (int j = 0; j < 4; ++j)
                acc[i][j] = __builtin_amdgcn_mfma_f32_16x16x32_f16(af[i], bf[j], acc[i][j], 0, 0, 0);
        __syncthreads();
    }

    float* outp = (gridDim.z == 1) ? Cc : (part + (long long)blockIdx.z * zstride);
    // C/D layout: col=lane&15, row=(lane>>4)*4+reg (m89-verified)
#pragma unroll
    for (int i = 0; i < 4; ++i)
#pragma unroll
        for (int j = 0; j < 4; ++j) {
            float* cp = outp + (m0 + wm + i * 16 + fq * 4) * ldc + (n0 + wn + j * 16 + fr);
#pragma unroll
            for (int r = 0; r < 4; ++r) cp[(long long)r * ldc] = acc[i][j][r];
        }
}

// ---------------- fallback reg-staged GEMM (f32 A), 8-wave ------------------
#define GLDH 40
template <typename TA>
static __device__ __forceinline__ hlf8 ld8f(const TA* p) {
    if constexpr (sizeof(TA) == 4) {
        float4 a = *(const float4*)(p + 0);
        float4 b = *(const float4*)(p + 4);
        hlf8 r = {(_Float16)a.x, (_Float16)a.y, (_Float16)a.z, (_Float16)a.w,
                  (_Float16)b.x, (_Float16)b.y, (_Float16)b.z, (_Float16)b.w};
        return r;
    } else {
        return *(const hlf8*)p;
    }
}

template <typename TA>
__global__ __launch_bounds__(512) void k_gemm8(
    const TA* __restrict__ A, int lda,
    const _Float16* __restrict__ B, int ldb,
    float* __restrict__ Cc, long long ldc, int K,
    float* __restrict__ part, long long zstride) {
    __shared__ _Float16 Ah[2][128 * GLDH];
    __shared__ _Float16 Bh[2][128 * GLDH];
    const int tid = threadIdx.x;
    const long long m0 = (long long)blockIdx.x * 128;
    const long long n0 = (long long)blockIdx.y * 128;
    const int KC = K / gridDim.z;
    const int kbase = blockIdx.z * KC;
    const int srow = tid >> 2, sseg = tid & 3;
    const TA* Ap = A + (m0 + srow) * (long long)lda + kbase + sseg * 8;
    const _Float16* Bp = B + (n0 + srow) * (long long)ldb + kbase + sseg * 8;
    const int lane = tid & 63, wv = tid >> 6;
    const int wm = (wv >> 2) * 64, wn = (wv & 3) * 32;
    const int fr = lane & 15, fq = lane >> 4;
    const int sOff = srow * GLDH + sseg * 8;

    f32x4 acc[4][2] = {};
    hlf8 ra, rb;
    ra = ld8f(Ap); rb = ld8f(Bp);
    *(hlf8*)&Ah[0][sOff] = ra; *(hlf8*)&Bh[0][sOff] = rb;
    __syncthreads();

    const int NT = KC / 32;
    for (int kt = 0; kt < NT; ++kt) {
        const int cur = kt & 1;
        if (kt + 1 < NT) {
            ra = ld8f(Ap + (long long)(kt + 1) * 32);
            rb = ld8f(Bp + (long long)(kt + 1) * 32);
        }
        hlf8 af[4], bf[2];
#pragma unroll
        for (int i = 0; i < 4; ++i)
            af[i] = *(const hlf8*)&Ah[cur][(wm + i * 16 + fr) * GLDH + fq * 8];
#pragma unroll
        for (int j = 0; j < 2; ++j)
            bf[j] = *(const hlf8*)&Bh[cur][(wn + j * 16 + fr) * GLDH + fq * 8];
#pragma unroll
        for (int i = 0; i < 4; ++i)
#pragma unroll
            for (int j = 0; j < 2; ++j)
                acc[i][j] = __builtin_amdgcn_mfma_f32_16x16x32_f16(af[i], bf[j], acc[i][j], 0, 0, 0);
        if (kt + 1 < NT) {
            const int nx = cur ^ 1;
            *(hlf8*)&Ah[nx][sOff] = ra; *(hlf8*)&Bh[nx][sOff] = rb;
        }
        __syncthreads();
    }

    float* outp = (gridDim.z == 1) ? Cc : (part + (long long)blockIdx.z * zstride);
#pragma unroll
    for (int i = 0; i < 4; ++i)
#pragma unroll
        for (int j = 0; j < 2; ++j) {
            float* cp = outp + (m0 + wm + i * 16 + fq * 4) * ldc + (n0 + wn + j * 16 + fr);
#pragma unroll
            for (int r = 0; r < 4; ++r) cp[(long long)r * ldc] = acc[i][j][r];
        }
}

// ---------------- split-K reduction: out = sum_z part[z] ----------------
__global__ __launch_bounds__(256) void k_redux(
    const float* __restrict__ part, float* __restrict__ out,
    long long n4, long long zs4, int Z) {
    long long i = blockIdx.x * 256ll + threadIdx.x;
    long long stride = (long long)gridDim.x * 256ll;
    for (; i < n4; i += stride) {
        float4 s = ((const float4*)part)[i];
        for (int z = 1; z < Z; ++z) {
            float4 t = ((const float4*)part)[i + z * zs4];
            s.x += t.x; s.y += t.y; s.z += t.z; s.w += t.w;
        }
        ((float4*)out)[i] = s;
    }
}

// ---------------- row LayerNorm in-place, width W = CNT*256 ----------------
template <int CNT>
__global__ __launch_bounds__(256) void k_layernorm(
    float* __restrict__ Y, const float* __restrict__ g,
    const float* __restrict__ b, int W) {
    float* yr = Y + (long long)blockIdx.x * W;
    float v[CNT];
    float s = 0.f;
#pragma unroll
    for (int i = 0; i < CNT; ++i) {
        v[i] = yr[threadIdx.x + (i << 8)];
        s += v[i];
    }
    float mu = blk_sum(s) / (float)W;
    float sq = 0.f;
#pragma unroll
    for (int i = 0; i < CNT; ++i) {
        float d = v[i] - mu;
        sq = fmaf(d, d, sq);
    }
    float var = blk_sum(sq) / (float)W;
    float rs = rsqrtf(var + 1e-5f);
#pragma unroll
    for (int i = 0; i < CNT; ++i) {
        int col = threadIdx.x + (i << 8);
        yr[col] = (v[i] - mu) * rs * g[col] + b[col];
    }
}

// -------- row softmax in-place, W = 16384; optional f16 copy of result ------
__global__ __launch_bounds__(256) void k_softmax(
    float* __restrict__ S, _Float16* __restrict__ Sh, float scale) {
    float* sr = S + (long long)blockIdx.x * 16384;
    _Float16* shr = Sh ? Sh + (long long)blockIdx.x * 16384 : nullptr;
    float4 r[16];
    float mx = -1e30f;
#pragma unroll
    for (int i = 0; i < 16; ++i) {
        float4 t = ((const float4*)sr)[threadIdx.x + (i << 8)];
        t.x *= scale; t.y *= scale; t.z *= scale; t.w *= scale;
        r[i] = t;
        mx = fmaxf(mx, fmaxf(fmaxf(t.x, t.y), fmaxf(t.z, t.w)));
    }
    mx = blk_max(mx);
    float sum = 0.f;
#pragma unroll
    for (int i = 0; i < 16; ++i) {
        float4 t = r[i];
        t.x = __expf(t.x - mx); t.y = __expf(t.y - mx);
        t.z = __expf(t.z - mx); t.w = __expf(t.w - mx);
        r[i] = t;
        sum += t.x + t.y + t.z + t.w;
    }
    sum = blk_sum(sum);
    float inv = 1.0f / sum;
#pragma unroll
    for (int i = 0; i < 16; ++i) {
        float4 t = r[i];
        t.x *= inv; t.y *= inv; t.z *= inv; t.w *= inv;
        ((float4*)sr)[threadIdx.x + (i << 8)] = t;
        if (shr) {
            hlf4 o = {(_Float16)t.x, (_Float16)t.y, (_Float16)t.z, (_Float16)t.w};
            ((hlf4*)shr)[threadIdx.x + (i << 8)] = o;
        }
    }
}

extern "C" void kernel_launch(void* const* d_in, const int* in_sizes, int n_in,
                              void* d_out, int out_size, void* d_ws, size_t ws_size,
                              hipStream_t stream) {
    const float* x      = (const float*)d_in[0];
    const float* X_data = (const float*)d_in[1];
    const int*   midx   = (const int*)d_in[2];
    const float* W_q    = (const float*)d_in[3];
    const float* W_k    = (const float*)d_in[4];
    const float* W_v    = (const float*)d_in[5];
    const float* g_q    = (const float*)d_in[6];
    const float* b_q    = (const float*)d_in[7];
    const float* g_k    = (const float*)d_in[8];
    const float* b_k    = (const float*)d_in[9];
    const float* g_v    = (const float*)d_in[10];
    const float* b_v    = (const float*)d_in[11];

    const int n  = in_sizes[10];        // 1024
    const int a  = in_sizes[6];         // 256
    const int m  = in_sizes[2];         // 16384
    const int Bn = in_sizes[0] / n;     // 4096

    // output layout: xs | x_hat | attn | v
    float* out  = (float*)d_out;
    float* xs   = out;
    float* xhat = xs + (long long)Bn * n;
    float* attn = xhat + (long long)Bn * n;
    float* vout = attn + (long long)Bn * m;

    // workspace carving (256B aligned). [qmat .. k_h] (~73 MB) is dead before
    // the x_hat GEMM, so the 64 MB split-K partial buffer aliases it.
    char* wp = (char*)d_ws;
    auto carve = [&](size_t bytes) -> char* {
        char* r = wp; wp += (bytes + 255) & ~(size_t)255; return r;
    };
    float*     norms = (float*)carve((size_t)m * 4);
    float*     cinv  = (float*)carve(16);
    char*      alias0 = wp;
    float*     qmat  = (float*)carve((size_t)Bn * a * 4);
    float*     kmat  = (float*)carve((size_t)m * a * 4);
    _Float16*  xs_h  = (_Float16*)carve((size_t)Bn * n * 2);
    _Float16*  Xc_h  = (_Float16*)carve((size_t)m * n * 2);
    _Float16*  Wq_h  = (_Float16*)carve((size_t)a * n * 2);
    _Float16*  Wk_h  = (_Float16*)carve((size_t)a * n * 2);
    _Float16*  Wv_h  = (_Float16*)carve((size_t)n * n * 2);
    _Float16*  q_h   = (_Float16*)carve((size_t)Bn * a * 2);
    _Float16*  k_h   = (_Float16*)carve((size_t)m * a * 2);
    float*     splitk = (float*)alias0;
    const int  SK = 4;                                    // SK*Bn*n*4 = 64MB <= 73MB
    _Float16*  vT_h  = (_Float16*)carve((size_t)n * m * 2);
    size_t used = (size_t)(wp - (char*)d_ws);
    _Float16* attn_h = nullptr;
    if (ws_size >= used + (size_t)Bn * m * 2 + 256)
        attn_h = (_Float16*)carve((size_t)Bn * m * 2);

    // 1) C normalizer
    hipLaunchKernelGGL(k_row_norms, dim3(m), dim3(256), 0, stream, X_data, midx, norms, n);
    hipLaunchKernelGGL(k_cinv, dim3(1), dim3(256), 0, stream, norms, m, n, cinv);

    // 2) xs = x/C (f32 + f16); gathered+scaled Xc in f16
    hipLaunchKernelGGL(k_scale2, dim3(2048), dim3(256), 0, stream,
                       x, cinv, xs, xs_h, (long long)Bn * n / 4);
    hipLaunchKernelGGL(k_gather_cvt, dim3(m), dim3(256), 0, stream,
                       X_data, midx, cinv, Xc_h, n);

    // 3) weights -> f16
    hipLaunchKernelGGL(k_cvt, dim3(256), dim3(256), 0, stream, W_q, Wq_h, (long long)a * n / 4);
    hipLaunchKernelGGL(k_cvt, dim3(256), dim3(256), 0, stream, W_k, Wk_h, (long long)a * n / 4);
    hipLaunchKernelGGL(k_cvt, dim3(1024), dim3(256), 0, stream, W_v, Wv_h, (long long)n * n / 4);

    // 4) projections (m97-structure MFMA)
    hipLaunchKernelGGL(k_gemm4, dim3(Bn / 128, a / 128), dim3(256), 0, stream,
                       xs_h, n, Wq_h, n, qmat, a, n, (float*)nullptr, 0ll);
    hipLaunchKernelGGL(k_gemm4, dim3(m / 128, a / 128), dim3(256), 0, stream,
                       Xc_h, n, Wk_h, n, kmat, a, n, (float*)nullptr, 0ll);
    hipLaunchKernelGGL(k_gemm4, dim3(m / 128, n / 128), dim3(256), 0, stream,
                       Xc_h, n, Wv_h, n, vout, n, n, (float*)nullptr, 0ll);

    // 5) LayerNorms (f32) + f16 copies of q,k and transposed v
    hipLaunchKernelGGL(k_layernorm<1>, dim3(Bn), dim3(256), 0, stream, qmat, g_q, b_q, a);
    hipLaunchKernelGGL(k_layernorm<1>, dim3(m),  dim3(256), 0, stream, kmat, g_k, b_k, a);
    hipLaunchKernelGGL(k_layernorm<4>, dim3(m),  dim3(256), 0, stream, vout, g_v, b_v, n);
    hipLaunchKernelGGL(k_cvt, dim3(1024), dim3(256), 0, stream, qmat, q_h, (long long)Bn * a / 4);
    hipLaunchKernelGGL(k_cvt, dim3(4096), dim3(256), 0, stream, kmat, k_h, (long long)m * a / 4);
    hipLaunchKernelGGL(k_tcvt, dim3(n / 32, m / 32), dim3(256), 0, stream, vout, vT_h, m, n);

    // 6) S = q k^T (f32 logits), softmax in place (+f16 copy)
    hipLaunchKernelGGL(k_gemm4, dim3(Bn / 128, m / 128), dim3(256), 0, stream,
                       q_h, a, k_h, a, attn, m, a, (float*)nullptr, 0ll);
    float sc = 1.0f / sqrtf((float)a);
    hipLaunchKernelGGL(k_softmax, dim3(Bn), dim3(256), 0, stream, attn, attn_h, sc);

    // 7) x_hat = attn @ v, split-K=4 into aliased partials, then reduce
    long long zstride = (long long)Bn * n;
    if (attn_h) {
        hipLaunchKernelGGL(k_gemm4, dim3(Bn / 128, n / 128, SK), dim3(256), 0, stream,
                           attn_h, m, vT_h, m, xhat, n, m, splitk, zstride);
    } else {
        hipLaunchKernelGGL((k_gemm8<float>), dim3(Bn / 128, n / 128, SK), dim3(512), 0, stream,
                           attn, m, vT_h, m, xhat, n, m, splitk, zstride);
    }
    hipLaunchKernelGGL(k_redux, dim3(2048), dim3(256), 0, stream,
                       splitk, xhat, (long long)Bn * n / 4, zstride / 4, SK);
}